// Round 4
// baseline (487.127 us; speedup 1.0000x reference)
//
#include <hip/hip_runtime.h>

// ---------------------------------------------------------------------------
// MHA forward: context = (softmax(mask(QK^T/sqrt(dk))) @ V) @ Wo^T + b
// Outputs: [context (2*2048*1024 f32)] ++ [attention (2*16*2048*2048 f32)]
// B=2 L=2048 DM=1024 H=16 DK=DV=64
// ---------------------------------------------------------------------------

typedef __attribute__((ext_vector_type(8))) short short8;   // 8 bf16
typedef __attribute__((ext_vector_type(4))) float f32x4;    // 4 f32 acc

#define MFMA_BF16(a,b,c) __builtin_amdgcn_mfma_f32_16x16x32_bf16((a),(b),(c),0,0,0)

__device__ __forceinline__ unsigned short f2bf(float f){   // RNE f32->bf16
  union { float f; unsigned u; } x; x.f = f;
  unsigned r = (x.u + 0x7fffu + ((x.u >> 16) & 1u)) >> 16;
  return (unsigned short)r;
}
__device__ __forceinline__ float bf2f(unsigned short h){
  union { unsigned u; float f; } x; x.u = ((unsigned)h) << 16; return x.f;
}

typedef __attribute__((address_space(1))) const void gas_void;
typedef __attribute__((address_space(3))) void las_void;
__device__ __forceinline__ void gload16(const void* g, void* l){
  __builtin_amdgcn_global_load_lds((gas_void*)g, (las_void*)l, 16, 0, 0);
}

// ------------------------------------------------- fused prep (1 kernel) ---
// blocks [0,4096): q hi/lo split     [4096,8192): k hi/lo split
// [8192,12288): v cast               [12288,13312): wq split
// [13312,14336): wk split            [14336,15360): wv cast
// [15360,16384): wo cast             [16384,24576): mask bit-pack
__global__ __launch_bounds__(256) void prep_k(
    const float* __restrict__ q, const float* __restrict__ k,
    const float* __restrict__ v, const int* __restrict__ mask,
    const float* __restrict__ wq, const float* __restrict__ wk,
    const float* __restrict__ wv, const float* __restrict__ wo,
    unsigned short* __restrict__ qhi, unsigned short* __restrict__ qlo,
    unsigned short* __restrict__ khi, unsigned short* __restrict__ klo,
    unsigned short* __restrict__ vb,
    unsigned short* __restrict__ wqh, unsigned short* __restrict__ wql,
    unsigned short* __restrict__ wkh, unsigned short* __restrict__ wkl,
    unsigned short* __restrict__ wvb, unsigned short* __restrict__ wob_,
    unsigned long long* __restrict__ bits){
  const int blk = blockIdx.x;
  if (blk >= 16384){                         // ---- mask pack ----
    int mb = blk - 16384;
    int base = mb*1024 + (threadIdx.x >> 6)*256;
    int lane = threadIdx.x & 63;
#pragma unroll
    for (int j=0;j<4;j++){
      unsigned long long w = __ballot(mask[base + j*64 + lane] != 0);
      if (lane == 0) bits[(base >> 6) + j] = w;
    }
    return;
  }
  const float* src; unsigned short *hi, *lo; bool split; int i;
  if (blk < 12288){
    i = (blk & 4095)*256 + threadIdx.x;
    if (blk < 4096){ src=q; hi=qhi; lo=qlo; split=true; }
    else if (blk < 8192){ src=k; hi=khi; lo=klo; split=true; }
    else { src=v; hi=vb; lo=nullptr; split=false; }
  } else {
    i = (blk & 1023)*256 + threadIdx.x;
    int seg = (blk - 12288) >> 10;
    if (seg==0){ src=wq; hi=wqh; lo=wql; split=true; }
    else if (seg==1){ src=wk; hi=wkh; lo=wkl; split=true; }
    else if (seg==2){ src=wv; hi=wvb; lo=nullptr; split=false; }
    else { src=wo; hi=wob_; lo=nullptr; split=false; }
  }
  float4 f = reinterpret_cast<const float4*>(src)[i];
  ushort4 oh;
  oh.x=f2bf(f.x); oh.y=f2bf(f.y); oh.z=f2bf(f.z); oh.w=f2bf(f.w);
  reinterpret_cast<ushort4*>(hi)[i] = oh;
  if (split){
    ushort4 ol;
    ol.x=f2bf(f.x - bf2f(oh.x)); ol.y=f2bf(f.y - bf2f(oh.y));
    ol.z=f2bf(f.z - bf2f(oh.z)); ol.w=f2bf(f.w - bf2f(oh.w));
    reinterpret_cast<ushort4*>(lo)[i] = ol;
  }
}

// --------------------------------------------- fused Q/K/V projections -----
__global__ __launch_bounds__(256,2) void proj_qkv_k(
    const unsigned short* __restrict__ qhi, const unsigned short* __restrict__ qlo,
    const unsigned short* __restrict__ khi, const unsigned short* __restrict__ klo,
    const unsigned short* __restrict__ vb,
    const unsigned short* __restrict__ wqh, const unsigned short* __restrict__ wql,
    const unsigned short* __restrict__ wkh, const unsigned short* __restrict__ wkl,
    const unsigned short* __restrict__ wvb,
    unsigned short* __restrict__ Qp, unsigned short* __restrict__ Kp,
    unsigned short* __restrict__ Vt){
  __shared__ __align__(16) char SA[2][2][8192];
  __shared__ __align__(16) char SB[2][2][8192];
  const int z = blockIdx.z;
  const bool SPLIT = (z < 2);
  const unsigned short *Ah, *Al, *Wh, *Wl;
  if (z==0){ Ah=qhi; Al=qlo; Wh=wqh; Wl=wql; }
  else if (z==1){ Ah=khi; Al=klo; Wh=wkh; Wl=wkl; }
  else { Ah=vb; Al=vb; Wh=wvb; Wl=wvb; }
  const int tid = threadIdx.x;
  const int wave = tid >> 6, lane = tid & 63;
  const int lr = lane & 15, lg = lane >> 4;
  const int m0 = blockIdx.y * 128, n0 = blockIdx.x * 128;
  const int wr = wave >> 1, wc = wave & 1;
  const f32x4 fz = {0.f,0.f,0.f,0.f};

  f32x4 acc[4][4];
#pragma unroll
  for (int i=0;i<4;i++)
#pragma unroll
    for (int j=0;j<4;j++) acc[i][j] = fz;

  auto stage = [&](int kt, int bu){
#pragma unroll
    for (int i=0;i<2;i++){
      int row = i*64 + (tid>>2);
      int kof = kt*32 + (tid&3)*8;
      size_t ga = (size_t)(m0+row)*1024 + kof;
      size_t gb = (size_t)(n0+row)*1024 + kof;
      int dof = i*4096 + wave*1024;
      gload16(Ah + ga, &SA[bu][0][dof]);
      gload16(Wh + gb, &SB[bu][0][dof]);
      if (SPLIT){
        gload16(Al + ga, &SA[bu][1][dof]);
        gload16(Wl + gb, &SB[bu][1][dof]);
      }
    }
  };
  stage(0,0);
  int buf = 0;
  for (int kt=0; kt<32; ++kt){
    __syncthreads();
    if (kt+1 < 32) stage(kt+1, buf^1);
    short8 fah[4], fal[4], fbh[4], fbl[4];
#pragma unroll
    for (int i=0;i<4;i++){
      int off = (wr*64+i*16+lr)*64 + lg*16;
      fah[i] = *(const short8*)(&SA[buf][0][off]);
      if (SPLIT) fal[i] = *(const short8*)(&SA[buf][1][off]);
    }
#pragma unroll
    for (int j=0;j<4;j++){
      int off = (wc*64+j*16+lr)*64 + lg*16;
      fbh[j] = *(const short8*)(&SB[buf][0][off]);
      if (SPLIT) fbl[j] = *(const short8*)(&SB[buf][1][off]);
    }
#pragma unroll
    for (int i=0;i<4;i++)
#pragma unroll
      for (int j=0;j<4;j++){
        acc[i][j] = MFMA_BF16(fah[i], fbh[j], acc[i][j]);
        if (SPLIT){
          acc[i][j] = MFMA_BF16(fal[i], fbh[j], acc[i][j]);
          acc[i][j] = MFMA_BF16(fah[i], fbl[j], acc[i][j]);
        }
      }
    buf ^= 1;
  }

  if (z < 2){
    unsigned short* out = (z==0) ? Qp : Kp;
#pragma unroll
    for (int i=0;i<4;i++)
#pragma unroll
      for (int j=0;j<4;j++)
#pragma unroll
        for (int r=0;r<4;r++){
          int m = m0 + wr*64 + i*16 + lg*4 + r;
          int n = n0 + wc*64 + j*16 + lr;
          out[(size_t)m*1024 + n] = f2bf(acc[i][j][r]);
        }
  } else {
#pragma unroll
    for (int i=0;i<4;i++)
#pragma unroll
      for (int j=0;j<4;j++){
        int m = m0 + wr*64 + i*16 + lg*4;
        int n = n0 + wc*64 + j*16 + lr;
        int b = m >> 11, lrow = m & 2047;
        int h = n >> 6,  dv = n & 63;
        ushort4 o;
        o.x = f2bf(acc[i][j][0]); o.y = f2bf(acc[i][j][1]);
        o.z = f2bf(acc[i][j][2]); o.w = f2bf(acc[i][j][3]);
        *reinterpret_cast<ushort4*>(Vt + ((size_t)((b*16+h)*64+dv))*2048 + lrow) = o;
      }
  }
}

// ----------------------------------------------------- attention pass 1 ----
// Row sums of masked exp(s); KVBLK=128, double-buffered; XCD-swizzled grid.
__global__ __launch_bounds__(256,3) void attn_pass1_k(
    const unsigned short* __restrict__ Qp, const unsigned short* __restrict__ Kp,
    const unsigned long long* __restrict__ mbits, float* __restrict__ linv){
  __shared__ __align__(16) char Ks[2][16384];
  const int tid = threadIdx.x;
  const int wave = tid >> 6, lane = tid & 63;
  const int lr = lane & 15, lg = lane >> 4;
  const int flat = blockIdx.x;                    // 512 blocks
  const int wg = ((flat & 7) << 6) + (flat >> 3); // XCD-contiguous
  const int bh = wg >> 4, b = bh >> 4, h = bh & 15;
  const int qbase = (wg & 15)*128 + wave*32;
  const f32x4 fz = {0.f,0.f,0.f,0.f};

  short8 qf[2][2];
#pragma unroll
  for (int ai=0;ai<2;ai++)
#pragma unroll
    for (int ks=0;ks<2;ks++)
      qf[ai][ks] = *(const short8*)(Qp + (size_t)(b*2048 + qbase + ai*16 + lr)*1024
                                    + h*64 + ks*32 + lg*8);
  float psum[2][4];
#pragma unroll
  for (int ai=0;ai<2;ai++)
#pragma unroll
    for (int r=0;r<4;r++) psum[ai][r] = 0.f;

  auto stageK = [&](int t, int bu){
#pragma unroll
    for (int i=0;i<4;i++){
      int byte = i*4096 + tid*16;
      int row = byte >> 7;
      int ch  = (byte >> 4) & 7;
      gload16(Kp + (size_t)(b*2048 + t*128 + row)*1024 + h*64 + ((ch ^ (row&7))*8),
              &Ks[bu][i*4096 + wave*1024]);
    }
  };
  stageK(0,0);
  int buf = 0;
  for (int t=0; t<16; ++t){
    __syncthreads();
    if (t+1 < 16) stageK(t+1, buf^1);
    f32x4 s[2][8];
#pragma unroll
    for (int ai=0;ai<2;ai++)
#pragma unroll
      for (int bj=0;bj<8;bj++) s[ai][bj] = fz;
#pragma unroll
    for (int ks=0;ks<2;ks++){
      short8 kf[8];
#pragma unroll
      for (int bj=0;bj<8;bj++){
        int row = bj*16 + lr;
        kf[bj] = *(const short8*)(&Ks[buf][row*128 + (((ks*4+lg) ^ (row&7))*16)]);
      }
#pragma unroll
      for (int ai=0;ai<2;ai++)
#pragma unroll
        for (int bj=0;bj<8;bj++)
          s[ai][bj] = MFMA_BF16(qf[ai][ks], kf[bj], s[ai][bj]);
    }
#pragma unroll
    for (int ai=0;ai<2;ai++)
#pragma unroll
      for (int r=0;r<4;r++){
        int qrow = qbase + ai*16 + lg*4 + r;
        ulonglong2 mw = *reinterpret_cast<const ulonglong2*>(
            mbits + (((size_t)(b*2048 + qrow)) << 5) + t*2);
        float a0 = 0.f;
#pragma unroll
        for (int bj=0;bj<8;bj++){
          unsigned long long w = (bj<4) ? mw.x : mw.y;
          int bit = (bj&3)*16 + lr;
          float e = __expf(s[ai][bj][r]*0.125f);
          a0 += ((w >> bit) & 1ull) ? e : 0.f;
        }
        psum[ai][r] += a0;
      }
    buf ^= 1;
  }
#pragma unroll
  for (int ai=0;ai<2;ai++)
#pragma unroll
    for (int r=0;r<4;r++){
      float v = psum[ai][r];
      v += __shfl_xor(v, 1, 64);
      v += __shfl_xor(v, 2, 64);
      v += __shfl_xor(v, 4, 64);
      v += __shfl_xor(v, 8, 64);
      if (lr == 0)
        linv[(size_t)bh*2048 + qbase + ai*16 + lg*4 + r] = 1.f / v;
    }
}

// ----------------------------------------------------- attention pass 2 ----
// KVBLK=64; p -> Ps (bf16); attention written from Ps via coalesced dwordx4
// (one aligned 128B line per lane per tile); PV accumulated from Ps/Vs.
__global__ __launch_bounds__(256,3) void attn_pass2_k(
    const unsigned short* __restrict__ Qp, const unsigned short* __restrict__ Kp,
    const unsigned short* __restrict__ Vt, const unsigned long long* __restrict__ mbits,
    const float* __restrict__ linv, float* __restrict__ attn,
    unsigned short* __restrict__ ctx){
  __shared__ __align__(16) char Ks[2][8192];
  __shared__ __align__(16) char Vs[2][8192];
  __shared__ __align__(16) unsigned short Ps[128*72];
  const int tid = threadIdx.x;
  const int wave = tid >> 6, lane = tid & 63;
  const int lr = lane & 15, lg = lane >> 4;
  const int flat = blockIdx.x;                    // 512 blocks
  const int wg = ((flat & 7) << 6) + (flat >> 3); // XCD-contiguous
  const int bh = wg >> 4, b = bh >> 4, h = bh & 15;
  const int qbase = (wg & 15)*128 + wave*32;
  const f32x4 fz = {0.f,0.f,0.f,0.f};

  short8 qf[2][2];
#pragma unroll
  for (int ai=0;ai<2;ai++)
#pragma unroll
    for (int ks=0;ks<2;ks++)
      qf[ai][ks] = *(const short8*)(Qp + (size_t)(b*2048 + qbase + ai*16 + lr)*1024
                                    + h*64 + ks*32 + lg*8);
  float li[2][4];
#pragma unroll
  for (int ai=0;ai<2;ai++)
#pragma unroll
    for (int r=0;r<4;r++)
      li[ai][r] = linv[(size_t)bh*2048 + qbase + ai*16 + lg*4 + r];

  f32x4 oacc[2][4];
#pragma unroll
  for (int ai=0;ai<2;ai++)
#pragma unroll
    for (int bj=0;bj<4;bj++) oacc[ai][bj] = fz;

  auto stageK = [&](int t, int bu){
#pragma unroll
    for (int i=0;i<2;i++){
      int byte = i*4096 + tid*16;
      int row = byte >> 7;
      int ch  = (byte >> 4) & 7;
      gload16(Kp + (size_t)(b*2048 + t*64 + row)*1024 + h*64 + ((ch ^ (row&7))*8),
              &Ks[bu][i*4096 + wave*1024]);
    }
  };
  auto stageV = [&](int t, int bu){
#pragma unroll
    for (int i=0;i<2;i++){
      int byte = i*4096 + tid*16;
      int row = byte >> 7;
      int ch  = (byte >> 4) & 7;
      gload16(Vt + (size_t)(bh*64 + row)*2048 + t*64 + ((ch ^ (row&7))*8),
              &Vs[bu][i*4096 + wave*1024]);
    }
  };
  stageK(0,0); stageV(0,0);
  int buf = 0;
  for (int t=0; t<32; ++t){
    __syncthreads();
    if (t+1 < 32){ stageK(t+1, buf^1); stageV(t+1, buf^1); }
    f32x4 s[2][4];
#pragma unroll
    for (int ai=0;ai<2;ai++)
#pragma unroll
      for (int bj=0;bj<4;bj++) s[ai][bj] = fz;
#pragma unroll
    for (int ks=0;ks<2;ks++){
      short8 kf[4];
#pragma unroll
      for (int bj=0;bj<4;bj++){
        int row = bj*16 + lr;
        kf[bj] = *(const short8*)(&Ks[buf][row*128 + (((ks*4+lg) ^ (row&7))*16)]);
      }
#pragma unroll
      for (int ai=0;ai<2;ai++)
#pragma unroll
        for (int bj=0;bj<4;bj++)
          s[ai][bj] = MFMA_BF16(qf[ai][ks], kf[bj], s[ai][bj]);
    }
#pragma unroll
    for (int ai=0;ai<2;ai++)
#pragma unroll
      for (int r=0;r<4;r++){
        int qrow = qbase + ai*16 + lg*4 + r;
        unsigned long long w = mbits[(((size_t)(b*2048 + qrow)) << 5) + t];
        unsigned short* prow = &Ps[(wave*32 + ai*16 + lg*4 + r)*72 + lr];
#pragma unroll
        for (int bj=0;bj<4;bj++){
          int bit = bj*16 + lr;
          float e = __expf(s[ai][bj][r]*0.125f);
          float p = ((w >> bit) & 1ull) ? e*li[ai][r] : 0.f;
          prow[bj*16] = f2bf(p);
        }
      }
    // coalesced attention write from Ps: lane owns one 128B line
    {
      int row = lane >> 1, half = lane & 1;
      const char* pbase = (const char*)Ps + (wave*32 + row)*144 + half*64;
      float* obase = attn + ((size_t)bh*2048 + qbase + row)*2048 + t*64 + half*32;
#pragma unroll
      for (int j=0;j<4;j++){
        short8 pv = *(const short8*)(pbase + j*16);
        f32x4 o0, o1;
        o0[0]=bf2f((unsigned short)pv[0]); o0[1]=bf2f((unsigned short)pv[1]);
        o0[2]=bf2f((unsigned short)pv[2]); o0[3]=bf2f((unsigned short)pv[3]);
        o1[0]=bf2f((unsigned short)pv[4]); o1[1]=bf2f((unsigned short)pv[5]);
        o1[2]=bf2f((unsigned short)pv[6]); o1[3]=bf2f((unsigned short)pv[7]);
        *reinterpret_cast<f32x4*>(obase + j*8)     = o0;
        *reinterpret_cast<f32x4*>(obase + j*8 + 4) = o1;
      }
    }
    // PV: O += P(128x64) @ V(64x64)
#pragma unroll
    for (int ks=0;ks<2;ks++){
      short8 pa[2];
#pragma unroll
      for (int ai=0;ai<2;ai++)
        pa[ai] = *(const short8*)((const char*)Ps
                   + (wave*32 + ai*16 + lr)*144 + ks*64 + lg*16);
      short8 vf[4];
#pragma unroll
      for (int bj=0;bj<4;bj++){
        int row = bj*16 + lr;
        vf[bj] = *(const short8*)(&Vs[buf][row*128 + (((ks*4+lg) ^ (row&7))*16)]);
      }
#pragma unroll
      for (int ai=0;ai<2;ai++)
#pragma unroll
        for (int bj=0;bj<4;bj++)
          oacc[ai][bj] = MFMA_BF16(pa[ai], vf[bj], oacc[ai][bj]);
    }
    buf ^= 1;
  }
#pragma unroll
  for (int ai=0;ai<2;ai++)
#pragma unroll
    for (int bj=0;bj<4;bj++)
#pragma unroll
      for (int r=0;r<4;r++){
        int qrow = qbase + ai*16 + lg*4 + r;
        int dv = bj*16 + lr;
        ctx[(size_t)(b*2048 + qrow)*1024 + h*64 + dv] = f2bf(oacc[ai][bj][r]);
      }
}

// --------------------------------------------------- out-proj (BM=64) ------
__global__ __launch_bounds__(256,4) void gemm_out_k(const unsigned short* __restrict__ A,
    const unsigned short* __restrict__ W, float* __restrict__ out,
    const float* __restrict__ bias){
  __shared__ __align__(16) char As[2][4096];
  __shared__ __align__(16) char Bs[2][8192];
  const int tid = threadIdx.x;
  const int wave = tid >> 6, lane = tid & 63;
  const int lr = lane & 15, lg = lane >> 4;
  const int m0 = blockIdx.y * 64, n0 = blockIdx.x * 128;
  const int wr = wave >> 1, wc = wave & 1;
  const f32x4 fz = {0.f,0.f,0.f,0.f};

  f32x4 acc[2][4];
#pragma unroll
  for (int i=0;i<2;i++)
#pragma unroll
    for (int j=0;j<4;j++) acc[i][j] = fz;

  auto stage = [&](int kt, int bu){
    int kof = kt*32 + (tid&3)*8;
    gload16(A + (size_t)(m0 + (tid>>2))*1024 + kof, &As[bu][wave*1024]);
#pragma unroll
    for (int i=0;i<2;i++){
      int row = i*64 + (tid>>2);
      gload16(W + (size_t)(n0+row)*1024 + kof, &Bs[bu][i*4096 + wave*1024]);
    }
  };
  stage(0,0);
  int buf = 0;
  for (int kt=0; kt<32; ++kt){
    __syncthreads();
    if (kt+1 < 32) stage(kt+1, buf^1);
    short8 af[2], bf[4];
#pragma unroll
    for (int i=0;i<2;i++) af[i] = *(const short8*)(&As[buf][(wr*32+i*16+lr)*64 + lg*16]);
#pragma unroll
    for (int j=0;j<4;j++) bf[j] = *(const short8*)(&Bs[buf][(wc*64+j*16+lr)*64 + lg*16]);
#pragma unroll
    for (int i=0;i<2;i++)
#pragma unroll
      for (int j=0;j<4;j++)
        acc[i][j] = MFMA_BF16(af[i], bf[j], acc[i][j]);
    buf ^= 1;
  }
#pragma unroll
  for (int i=0;i<2;i++)
#pragma unroll
    for (int j=0;j<4;j++){
      int n = n0 + wc*64 + j*16 + lr;
      float bv = bias[n];
#pragma unroll
      for (int r=0;r<4;r++){
        int m = m0 + wr*32 + i*16 + lg*4 + r;
        out[(size_t)m*1024 + n] = acc[i][j][r] + bv;
      }
    }
}

// ------------------------------------------------------------------ host ---
extern "C" void kernel_launch(void* const* d_in, const int* in_sizes, int n_in,
                              void* d_out, int out_size, void* d_ws, size_t ws_size,
                              hipStream_t stream){
  (void)in_sizes; (void)n_in; (void)out_size;
  const float* q   = (const float*)d_in[0];
  const float* k   = (const float*)d_in[1];
  const float* v   = (const float*)d_in[2];
  const int*  mask = (const int*)d_in[3];
  const float* wq  = (const float*)d_in[4];
  const float* wk  = (const float*)d_in[5];
  const float* wv  = (const float*)d_in[6];
  const float* wo  = (const float*)d_in[7];
  const float* wob = (const float*)d_in[8];

  char* ws = (char*)d_ws;
  const size_t MB = 1ull << 20;
  unsigned short* qhi = (unsigned short*)(ws +  0*MB);
  unsigned short* qlo = (unsigned short*)(ws +  8*MB);
  unsigned short* khi = (unsigned short*)(ws + 16*MB);
  unsigned short* klo = (unsigned short*)(ws + 24*MB);
  unsigned short* vb  = (unsigned short*)(ws + 32*MB);
  unsigned short* wqh = (unsigned short*)(ws + 40*MB);
  unsigned short* wql = (unsigned short*)(ws + 42*MB);
  unsigned short* wkh = (unsigned short*)(ws + 44*MB);
  unsigned short* wkl = (unsigned short*)(ws + 46*MB);
  unsigned short* wvb = (unsigned short*)(ws + 48*MB);
  unsigned short* wob_= (unsigned short*)(ws + 50*MB);   // 2 MB: [50,52)
  unsigned short* Qp  = (unsigned short*)(ws + 52*MB);
  unsigned short* Kp  = (unsigned short*)(ws + 60*MB);
  unsigned short* Vt  = (unsigned short*)(ws + 68*MB);
  unsigned short* Ctx = (unsigned short*)(ws + 76*MB);
  unsigned long long* mbits = (unsigned long long*)(ws + 84*MB);
  // lin (256 KB) reuses the qhi region: qhi is dead after proj_qkv_k, and
  // attn_pass1_k (which writes lin) runs strictly after it on this stream.
  float*          lin = (float*)(ws + 0*MB);
  if (ws_size < 85*MB) return;   // need 85 MB scratch

  float* ctx_out  = (float*)d_out;
  float* attn_out = ctx_out + (size_t)2*2048*1024;

  prep_k<<<24576,256,0,stream>>>(q,k,v,mask,wq,wk,wv,wo,
                                 qhi,qlo,khi,klo,vb,
                                 wqh,wql,wkh,wkl,wvb,wob_, mbits);

  proj_qkv_k<<<dim3(8,32,3),256,0,stream>>>(qhi,qlo,khi,klo,vb,
                                            wqh,wql,wkh,wkl,wvb, Qp,Kp,Vt);

  attn_pass1_k<<<512,256,0,stream>>>(Qp, Kp, mbits, lin);
  attn_pass2_k<<<512,256,0,stream>>>(Qp, Kp, Vt, mbits, lin,
                                     attn_out, Ctx);

  gemm_out_k<<<dim3(8,64),256,0,stream>>>(Ctx, wob_, ctx_out, wob);
}

// Round 5
// 384.432 us; speedup vs baseline: 1.2671x; 1.2671x over previous
//
#include <hip/hip_runtime.h>

// ---------------------------------------------------------------------------
// MHA forward: context = (softmax(mask(QK^T/sqrt(dk))) @ V) @ Wo^T + b
// Outputs: [context (2*2048*1024 f32)] ++ [attention (2*16*2048*2048 f32)]
// B=2 L=2048 DM=1024 H=16 DK=DV=64
// ---------------------------------------------------------------------------

typedef __attribute__((ext_vector_type(8))) short short8;   // 8 bf16
typedef __attribute__((ext_vector_type(4))) float f32x4;    // 4 f32 acc

#define MFMA_BF16(a,b,c) __builtin_amdgcn_mfma_f32_16x16x32_bf16((a),(b),(c),0,0,0)

__device__ __forceinline__ unsigned short f2bf(float f){   // RNE f32->bf16
  union { float f; unsigned u; } x; x.f = f;
  unsigned r = (x.u + 0x7fffu + ((x.u >> 16) & 1u)) >> 16;
  return (unsigned short)r;
}
__device__ __forceinline__ float bf2f(unsigned short h){
  union { unsigned u; float f; } x; x.u = ((unsigned)h) << 16; return x.f;
}

typedef __attribute__((address_space(1))) const void gas_void;
typedef __attribute__((address_space(3))) void las_void;
__device__ __forceinline__ void gload16(const void* g, void* l){
  __builtin_amdgcn_global_load_lds((gas_void*)g, (las_void*)l, 16, 0, 0);
}

// ------------------------------------------------- fused prep (1 kernel) ---
__global__ __launch_bounds__(256) void prep_k(
    const float* __restrict__ q, const float* __restrict__ k,
    const float* __restrict__ v, const int* __restrict__ mask,
    const float* __restrict__ wq, const float* __restrict__ wk,
    const float* __restrict__ wv, const float* __restrict__ wo,
    unsigned short* __restrict__ qhi, unsigned short* __restrict__ qlo,
    unsigned short* __restrict__ khi, unsigned short* __restrict__ klo,
    unsigned short* __restrict__ vb,
    unsigned short* __restrict__ wqh, unsigned short* __restrict__ wql,
    unsigned short* __restrict__ wkh, unsigned short* __restrict__ wkl,
    unsigned short* __restrict__ wvb, unsigned short* __restrict__ wob_,
    unsigned long long* __restrict__ bits){
  const int blk = blockIdx.x;
  if (blk >= 16384){                         // ---- mask pack ----
    int mb = blk - 16384;
    int base = mb*1024 + (threadIdx.x >> 6)*256;
    int lane = threadIdx.x & 63;
#pragma unroll
    for (int j=0;j<4;j++){
      unsigned long long w = __ballot(mask[base + j*64 + lane] != 0);
      if (lane == 0) bits[(base >> 6) + j] = w;
    }
    return;
  }
  const float* src; unsigned short *hi, *lo; bool split; int i;
  if (blk < 12288){
    i = (blk & 4095)*256 + threadIdx.x;
    if (blk < 4096){ src=q; hi=qhi; lo=qlo; split=true; }
    else if (blk < 8192){ src=k; hi=khi; lo=klo; split=true; }
    else { src=v; hi=vb; lo=nullptr; split=false; }
  } else {
    i = (blk & 1023)*256 + threadIdx.x;
    int seg = (blk - 12288) >> 10;
    if (seg==0){ src=wq; hi=wqh; lo=wql; split=true; }
    else if (seg==1){ src=wk; hi=wkh; lo=wkl; split=true; }
    else if (seg==2){ src=wv; hi=wvb; lo=nullptr; split=false; }
    else { src=wo; hi=wob_; lo=nullptr; split=false; }
  }
  float4 f = reinterpret_cast<const float4*>(src)[i];
  ushort4 oh;
  oh.x=f2bf(f.x); oh.y=f2bf(f.y); oh.z=f2bf(f.z); oh.w=f2bf(f.w);
  reinterpret_cast<ushort4*>(hi)[i] = oh;
  if (split){
    ushort4 ol;
    ol.x=f2bf(f.x - bf2f(oh.x)); ol.y=f2bf(f.y - bf2f(oh.y));
    ol.z=f2bf(f.z - bf2f(oh.z)); ol.w=f2bf(f.w - bf2f(oh.w));
    reinterpret_cast<ushort4*>(lo)[i] = ol;
  }
}

// --------------------------------------------- fused Q/K/V projections -----
__global__ __launch_bounds__(256,2) void proj_qkv_k(
    const unsigned short* __restrict__ qhi, const unsigned short* __restrict__ qlo,
    const unsigned short* __restrict__ khi, const unsigned short* __restrict__ klo,
    const unsigned short* __restrict__ vb,
    const unsigned short* __restrict__ wqh, const unsigned short* __restrict__ wql,
    const unsigned short* __restrict__ wkh, const unsigned short* __restrict__ wkl,
    const unsigned short* __restrict__ wvb,
    unsigned short* __restrict__ Qp, unsigned short* __restrict__ Kp,
    unsigned short* __restrict__ Vt){
  __shared__ __align__(16) char SA[2][2][8192];
  __shared__ __align__(16) char SB[2][2][8192];
  const int z = blockIdx.z;
  const bool SPLIT = (z < 2);
  const unsigned short *Ah, *Al, *Wh, *Wl;
  if (z==0){ Ah=qhi; Al=qlo; Wh=wqh; Wl=wql; }
  else if (z==1){ Ah=khi; Al=klo; Wh=wkh; Wl=wkl; }
  else { Ah=vb; Al=vb; Wh=wvb; Wl=wvb; }
  const int tid = threadIdx.x;
  const int wave = tid >> 6, lane = tid & 63;
  const int lr = lane & 15, lg = lane >> 4;
  const int m0 = blockIdx.y * 128, n0 = blockIdx.x * 128;
  const int wr = wave >> 1, wc = wave & 1;
  const f32x4 fz = {0.f,0.f,0.f,0.f};

  f32x4 acc[4][4];
#pragma unroll
  for (int i=0;i<4;i++)
#pragma unroll
    for (int j=0;j<4;j++) acc[i][j] = fz;

  auto stage = [&](int kt, int bu){
#pragma unroll
    for (int i=0;i<2;i++){
      int row = i*64 + (tid>>2);
      int kof = kt*32 + (tid&3)*8;
      size_t ga = (size_t)(m0+row)*1024 + kof;
      size_t gb = (size_t)(n0+row)*1024 + kof;
      int dof = i*4096 + wave*1024;
      gload16(Ah + ga, &SA[bu][0][dof]);
      gload16(Wh + gb, &SB[bu][0][dof]);
      if (SPLIT){
        gload16(Al + ga, &SA[bu][1][dof]);
        gload16(Wl + gb, &SB[bu][1][dof]);
      }
    }
  };
  stage(0,0);
  int buf = 0;
  for (int kt=0; kt<32; ++kt){
    __syncthreads();
    if (kt+1 < 32) stage(kt+1, buf^1);
    short8 fah[4], fal[4], fbh[4], fbl[4];
#pragma unroll
    for (int i=0;i<4;i++){
      int off = (wr*64+i*16+lr)*64 + lg*16;
      fah[i] = *(const short8*)(&SA[buf][0][off]);
      if (SPLIT) fal[i] = *(const short8*)(&SA[buf][1][off]);
    }
#pragma unroll
    for (int j=0;j<4;j++){
      int off = (wc*64+j*16+lr)*64 + lg*16;
      fbh[j] = *(const short8*)(&SB[buf][0][off]);
      if (SPLIT) fbl[j] = *(const short8*)(&SB[buf][1][off]);
    }
#pragma unroll
    for (int i=0;i<4;i++)
#pragma unroll
      for (int j=0;j<4;j++){
        acc[i][j] = MFMA_BF16(fah[i], fbh[j], acc[i][j]);
        if (SPLIT){
          acc[i][j] = MFMA_BF16(fal[i], fbh[j], acc[i][j]);
          acc[i][j] = MFMA_BF16(fah[i], fbl[j], acc[i][j]);
        }
      }
    buf ^= 1;
  }

  if (z < 2){
    unsigned short* out = (z==0) ? Qp : Kp;
#pragma unroll
    for (int i=0;i<4;i++)
#pragma unroll
      for (int j=0;j<4;j++)
#pragma unroll
        for (int r=0;r<4;r++){
          int m = m0 + wr*64 + i*16 + lg*4 + r;
          int n = n0 + wc*64 + j*16 + lr;
          out[(size_t)m*1024 + n] = f2bf(acc[i][j][r]);
        }
  } else {
#pragma unroll
    for (int i=0;i<4;i++)
#pragma unroll
      for (int j=0;j<4;j++){
        int m = m0 + wr*64 + i*16 + lg*4;
        int n = n0 + wc*64 + j*16 + lr;
        int b = m >> 11, lrow = m & 2047;
        int h = n >> 6,  dv = n & 63;
        ushort4 o;
        o.x = f2bf(acc[i][j][0]); o.y = f2bf(acc[i][j][1]);
        o.z = f2bf(acc[i][j][2]); o.w = f2bf(acc[i][j][3]);
        *reinterpret_cast<ushort4*>(Vt + ((size_t)((b*16+h)*64+dv))*2048 + lrow) = o;
      }
  }
}

// ----------------------------------------------------- attention pass 1 ----
__global__ __launch_bounds__(256,3) void attn_pass1_k(
    const unsigned short* __restrict__ Qp, const unsigned short* __restrict__ Kp,
    const unsigned long long* __restrict__ mbits, float* __restrict__ linv){
  __shared__ __align__(16) char Ks[2][16384];
  const int tid = threadIdx.x;
  const int wave = tid >> 6, lane = tid & 63;
  const int lr = lane & 15, lg = lane >> 4;
  const int flat = blockIdx.x;                    // 512 blocks
  const int wg = ((flat & 7) << 6) + (flat >> 3); // XCD-contiguous
  const int bh = wg >> 4, b = bh >> 4, h = bh & 15;
  const int qbase = (wg & 15)*128 + wave*32;
  const f32x4 fz = {0.f,0.f,0.f,0.f};

  short8 qf[2][2];
#pragma unroll
  for (int ai=0;ai<2;ai++)
#pragma unroll
    for (int ks=0;ks<2;ks++)
      qf[ai][ks] = *(const short8*)(Qp + (size_t)(b*2048 + qbase + ai*16 + lr)*1024
                                    + h*64 + ks*32 + lg*8);
  float psum[2][4];
#pragma unroll
  for (int ai=0;ai<2;ai++)
#pragma unroll
    for (int r=0;r<4;r++) psum[ai][r] = 0.f;

  auto stageK = [&](int t, int bu){
#pragma unroll
    for (int i=0;i<4;i++){
      int byte = i*4096 + tid*16;
      int row = byte >> 7;
      int ch  = (byte >> 4) & 7;
      gload16(Kp + (size_t)(b*2048 + t*128 + row)*1024 + h*64 + ((ch ^ (row&7))*8),
              &Ks[bu][i*4096 + wave*1024]);
    }
  };
  stageK(0,0);
  int buf = 0;
  for (int t=0; t<16; ++t){
    __syncthreads();
    if (t+1 < 16) stageK(t+1, buf^1);
    f32x4 s[2][8];
#pragma unroll
    for (int ai=0;ai<2;ai++)
#pragma unroll
      for (int bj=0;bj<8;bj++) s[ai][bj] = fz;
#pragma unroll
    for (int ks=0;ks<2;ks++){
      short8 kf[8];
#pragma unroll
      for (int bj=0;bj<8;bj++){
        int row = bj*16 + lr;
        kf[bj] = *(const short8*)(&Ks[buf][row*128 + (((ks*4+lg) ^ (row&7))*16)]);
      }
#pragma unroll
      for (int ai=0;ai<2;ai++)
#pragma unroll
        for (int bj=0;bj<8;bj++)
          s[ai][bj] = MFMA_BF16(qf[ai][ks], kf[bj], s[ai][bj]);
    }
#pragma unroll
    for (int ai=0;ai<2;ai++)
#pragma unroll
      for (int r=0;r<4;r++){
        int qrow = qbase + ai*16 + lg*4 + r;
        ulonglong2 mw = *reinterpret_cast<const ulonglong2*>(
            mbits + (((size_t)(b*2048 + qrow)) << 5) + t*2);
        float a0 = 0.f;
#pragma unroll
        for (int bj=0;bj<8;bj++){
          unsigned long long w = (bj<4) ? mw.x : mw.y;
          int bit = (bj&3)*16 + lr;
          float e = __expf(s[ai][bj][r]*0.125f);
          a0 += ((w >> bit) & 1ull) ? e : 0.f;
        }
        psum[ai][r] += a0;
      }
    buf ^= 1;
  }
#pragma unroll
  for (int ai=0;ai<2;ai++)
#pragma unroll
    for (int r=0;r<4;r++){
      float v = psum[ai][r];
      v += __shfl_xor(v, 1, 64);
      v += __shfl_xor(v, 2, 64);
      v += __shfl_xor(v, 4, 64);
      v += __shfl_xor(v, 8, 64);
      if (lr == 0)
        linv[(size_t)bh*2048 + qbase + ai*16 + lg*4 + r] = 1.f / v;
    }
}

// ----------------------------------------------------- attention pass 2 ----
// KVBLK=64; p written straight from registers (f32, overlap with MFMA) and
// to Ps (bf16, stride 72) for the PV MFMA.
__global__ __launch_bounds__(256,3) void attn_pass2_k(
    const unsigned short* __restrict__ Qp, const unsigned short* __restrict__ Kp,
    const unsigned short* __restrict__ Vt, const unsigned long long* __restrict__ mbits,
    const float* __restrict__ linv, float* __restrict__ attn,
    unsigned short* __restrict__ ctx){
  __shared__ __align__(16) char Ks[2][8192];
  __shared__ __align__(16) char Vs[2][8192];
  __shared__ __align__(16) unsigned short Ps[128*72];
  const int tid = threadIdx.x;
  const int wave = tid >> 6, lane = tid & 63;
  const int lr = lane & 15, lg = lane >> 4;
  const int flat = blockIdx.x;                    // 512 blocks
  const int wg = ((flat & 7) << 6) + (flat >> 3); // XCD-contiguous
  const int bh = wg >> 4, b = bh >> 4, h = bh & 15;
  const int qbase = (wg & 15)*128 + wave*32;
  const f32x4 fz = {0.f,0.f,0.f,0.f};

  short8 qf[2][2];
#pragma unroll
  for (int ai=0;ai<2;ai++)
#pragma unroll
    for (int ks=0;ks<2;ks++)
      qf[ai][ks] = *(const short8*)(Qp + (size_t)(b*2048 + qbase + ai*16 + lr)*1024
                                    + h*64 + ks*32 + lg*8);
  float li[2][4];
#pragma unroll
  for (int ai=0;ai<2;ai++)
#pragma unroll
    for (int r=0;r<4;r++)
      li[ai][r] = linv[(size_t)bh*2048 + qbase + ai*16 + lg*4 + r];

  f32x4 oacc[2][4];
#pragma unroll
  for (int ai=0;ai<2;ai++)
#pragma unroll
    for (int bj=0;bj<4;bj++) oacc[ai][bj] = fz;

  auto stageK = [&](int t, int bu){
#pragma unroll
    for (int i=0;i<2;i++){
      int byte = i*4096 + tid*16;
      int row = byte >> 7;
      int ch  = (byte >> 4) & 7;
      gload16(Kp + (size_t)(b*2048 + t*64 + row)*1024 + h*64 + ((ch ^ (row&7))*8),
              &Ks[bu][i*4096 + wave*1024]);
    }
  };
  auto stageV = [&](int t, int bu){
#pragma unroll
    for (int i=0;i<2;i++){
      int byte = i*4096 + tid*16;
      int row = byte >> 7;
      int ch  = (byte >> 4) & 7;
      gload16(Vt + (size_t)(bh*64 + row)*2048 + t*64 + ((ch ^ (row&7))*8),
              &Vs[bu][i*4096 + wave*1024]);
    }
  };
  stageK(0,0); stageV(0,0);
  int buf = 0;
  for (int t=0; t<32; ++t){
    __syncthreads();
    if (t+1 < 32){ stageK(t+1, buf^1); stageV(t+1, buf^1); }
    f32x4 s[2][4];
#pragma unroll
    for (int ai=0;ai<2;ai++)
#pragma unroll
      for (int bj=0;bj<4;bj++) s[ai][bj] = fz;
#pragma unroll
    for (int ks=0;ks<2;ks++){
      short8 kf[4];
#pragma unroll
      for (int bj=0;bj<4;bj++){
        int row = bj*16 + lr;
        kf[bj] = *(const short8*)(&Ks[buf][row*128 + (((ks*4+lg) ^ (row&7))*16)]);
      }
#pragma unroll
      for (int ai=0;ai<2;ai++)
#pragma unroll
        for (int bj=0;bj<4;bj++)
          s[ai][bj] = MFMA_BF16(qf[ai][ks], kf[bj], s[ai][bj]);
    }
#pragma unroll
    for (int ai=0;ai<2;ai++)
#pragma unroll
      for (int r=0;r<4;r++){
        int qrow = qbase + ai*16 + lg*4 + r;
        unsigned long long w = mbits[(((size_t)(b*2048 + qrow)) << 5) + t];
        float* arow = attn + ((size_t)bh*2048 + qrow)*2048 + t*64 + lr;
        unsigned short* prow = &Ps[(wave*32 + ai*16 + lg*4 + r)*72 + lr];
#pragma unroll
        for (int bj=0;bj<4;bj++){
          int bit = bj*16 + lr;
          float e = __expf(s[ai][bj][r]*0.125f);
          float p = ((w >> bit) & 1ull) ? e*li[ai][r] : 0.f;
          arow[bj*16] = p;
          prow[bj*16] = f2bf(p);
        }
      }
    // PV: O += P(128x64) @ V(64x64)
#pragma unroll
    for (int ks=0;ks<2;ks++){
      short8 pa[2];
#pragma unroll
      for (int ai=0;ai<2;ai++)
        pa[ai] = *(const short8*)((const char*)Ps
                   + (wave*32 + ai*16 + lr)*144 + ks*64 + lg*16);
      short8 vf[4];
#pragma unroll
      for (int bj=0;bj<4;bj++){
        int row = bj*16 + lr;
        vf[bj] = *(const short8*)(&Vs[buf][row*128 + (((ks*4+lg) ^ (row&7))*16)]);
      }
#pragma unroll
      for (int ai=0;ai<2;ai++)
#pragma unroll
        for (int bj=0;bj<4;bj++)
          oacc[ai][bj] = MFMA_BF16(pa[ai], vf[bj], oacc[ai][bj]);
    }
    buf ^= 1;
  }
#pragma unroll
  for (int ai=0;ai<2;ai++)
#pragma unroll
    for (int bj=0;bj<4;bj++)
#pragma unroll
      for (int r=0;r<4;r++){
        int qrow = qbase + ai*16 + lg*4 + r;
        int dv = bj*16 + lr;
        ctx[(size_t)(b*2048 + qrow)*1024 + h*64 + dv] = f2bf(oacc[ai][bj][r]);
      }
}

// --------------------------------------------------- out-proj (BM=64) ------
__global__ __launch_bounds__(256,4) void gemm_out_k(const unsigned short* __restrict__ A,
    const unsigned short* __restrict__ W, float* __restrict__ out,
    const float* __restrict__ bias){
  __shared__ __align__(16) char As[2][4096];
  __shared__ __align__(16) char Bs[2][8192];
  const int tid = threadIdx.x;
  const int wave = tid >> 6, lane = tid & 63;
  const int lr = lane & 15, lg = lane >> 4;
  const int m0 = blockIdx.y * 64, n0 = blockIdx.x * 128;
  const int wr = wave >> 1, wc = wave & 1;
  const f32x4 fz = {0.f,0.f,0.f,0.f};

  f32x4 acc[2][4];
#pragma unroll
  for (int i=0;i<2;i++)
#pragma unroll
    for (int j=0;j<4;j++) acc[i][j] = fz;

  auto stage = [&](int kt, int bu){
    int kof = kt*32 + (tid&3)*8;
    gload16(A + (size_t)(m0 + (tid>>2))*1024 + kof, &As[bu][wave*1024]);
#pragma unroll
    for (int i=0;i<2;i++){
      int row = i*64 + (tid>>2);
      gload16(W + (size_t)(n0+row)*1024 + kof, &Bs[bu][i*4096 + wave*1024]);
    }
  };
  stage(0,0);
  int buf = 0;
  for (int kt=0; kt<32; ++kt){
    __syncthreads();
    if (kt+1 < 32) stage(kt+1, buf^1);
    short8 af[2], bf[4];
#pragma unroll
    for (int i=0;i<2;i++) af[i] = *(const short8*)(&As[buf][(wr*32+i*16+lr)*64 + lg*16]);
#pragma unroll
    for (int j=0;j<4;j++) bf[j] = *(const short8*)(&Bs[buf][(wc*64+j*16+lr)*64 + lg*16]);
#pragma unroll
    for (int i=0;i<2;i++)
#pragma unroll
      for (int j=0;j<4;j++)
        acc[i][j] = MFMA_BF16(af[i], bf[j], acc[i][j]);
    buf ^= 1;
  }
#pragma unroll
  for (int i=0;i<2;i++)
#pragma unroll
    for (int j=0;j<4;j++){
      int n = n0 + wc*64 + j*16 + lr;
      float bv = bias[n];
#pragma unroll
      for (int r=0;r<4;r++){
        int m = m0 + wr*32 + i*16 + lg*4 + r;
        out[(size_t)m*1024 + n] = acc[i][j][r] + bv;
      }
    }
}

// ------------------------------------------------------------------ host ---
extern "C" void kernel_launch(void* const* d_in, const int* in_sizes, int n_in,
                              void* d_out, int out_size, void* d_ws, size_t ws_size,
                              hipStream_t stream){
  (void)in_sizes; (void)n_in; (void)out_size;
  const float* q   = (const float*)d_in[0];
  const float* k   = (const float*)d_in[1];
  const float* v   = (const float*)d_in[2];
  const int*  mask = (const int*)d_in[3];
  const float* wq  = (const float*)d_in[4];
  const float* wk  = (const float*)d_in[5];
  const float* wv  = (const float*)d_in[6];
  const float* wo  = (const float*)d_in[7];
  const float* wob = (const float*)d_in[8];

  char* ws = (char*)d_ws;
  const size_t MB = 1ull << 20;
  unsigned short* qhi = (unsigned short*)(ws +  0*MB);
  unsigned short* qlo = (unsigned short*)(ws +  8*MB);
  unsigned short* khi = (unsigned short*)(ws + 16*MB);
  unsigned short* klo = (unsigned short*)(ws + 24*MB);
  unsigned short* vb  = (unsigned short*)(ws + 32*MB);
  unsigned short* wqh = (unsigned short*)(ws + 40*MB);
  unsigned short* wql = (unsigned short*)(ws + 42*MB);
  unsigned short* wkh = (unsigned short*)(ws + 44*MB);
  unsigned short* wkl = (unsigned short*)(ws + 46*MB);
  unsigned short* wvb = (unsigned short*)(ws + 48*MB);
  unsigned short* wob_= (unsigned short*)(ws + 50*MB);   // 2 MB: [50,52)
  unsigned short* Qp  = (unsigned short*)(ws + 52*MB);
  unsigned short* Kp  = (unsigned short*)(ws + 60*MB);
  unsigned short* Vt  = (unsigned short*)(ws + 68*MB);
  unsigned short* Ctx = (unsigned short*)(ws + 76*MB);
  unsigned long long* mbits = (unsigned long long*)(ws + 84*MB);
  // lin (256 KB) reuses the qhi region: qhi is dead after proj_qkv_k.
  float*          lin = (float*)(ws + 0*MB);
  if (ws_size < 85*MB) return;   // need 85 MB scratch

  float* ctx_out  = (float*)d_out;
  float* attn_out = ctx_out + (size_t)2*2048*1024;

  prep_k<<<24576,256,0,stream>>>(q,k,v,mask,wq,wk,wv,wo,
                                 qhi,qlo,khi,klo,vb,
                                 wqh,wql,wkh,wkl,wvb,wob_, mbits);

  proj_qkv_k<<<dim3(8,32,3),256,0,stream>>>(qhi,qlo,khi,klo,vb,
                                            wqh,wql,wkh,wkl,wvb, Qp,Kp,Vt);

  attn_pass1_k<<<512,256,0,stream>>>(Qp, Kp, mbits, lin);
  attn_pass2_k<<<512,256,0,stream>>>(Qp, Kp, Vt, mbits, lin,
                                     attn_out, Ctx);

  gemm_out_k<<<dim3(8,64),256,0,stream>>>(Ctx, wob_, ctx_out, wob);
}